// Round 9
// baseline (678.704 us; speedup 1.0000x reference)
//
#include <hip/hip_runtime.h>
#include <math.h>

// Problem constants (B=8, T=256 -> 2048 independent (b,t) pipelines)
// R14: occupancy-doubling package. R13 (641 us): VALU 60%, MFMA 19%, HBM 0,
// occupancy pinned at 4 blk/CU because unified regs = 64 arch + 32 acc = 96.
// If unified fits <=64, HW grants 8 waves/SIMD -> 8 blk/CU -> ALL 2048
// blocks resident in one round. Co-designed changes (all bit-exact):
//  - acc[1][4] (16 AGPR), 6 m-passes, per-mt kt-trim (dropped products are
//    exactly-zero A fragments -> accumulators bit-identical; MFMA 264->240).
//  - __launch_bounds__(256, 8): forces unified <=64. Gate: WRITE_SIZE.
//  - u32 rank keys (float bits of squares, monotone) + EXACT ties via
//    per-wave range split (i<tid uniform-true region uses >=, uniform-false
//    uses >, only 16 boundary uint4s need the eq&&idx term). Rank LDS
//    broadcast traffic halves (was ~30% of the LDS pipe).
//  - mask arrays as u8 (values are small ints, exactly convertible) ->
//    LDS ~17.7KB <= 20KB -> 8 blocks/CU fits.
#define NBT 2048

typedef __attribute__((ext_vector_type(8))) short short8;     // 8 bf16 (4 VGPRs)
typedef __attribute__((ext_vector_type(4))) float floatx4;    // MFMA C/D

struct SM {
  alignas(16) float xp[240];        // zero-padded encoder input (nonzero in [80,160))
  alignas(16) short xhr[8][264];    // rotated bf16-hi copies: xhr[c][i] = hi(xp[c+i])
  alignas(16) short xlr[8][264];    // rotated bf16-lo copies
  alignas(16) unsigned hkey[256];   // rank keys: float bits of vsq (>=0, monotone)
  alignas(16) float yres[80];
  alignas(16) float beL[256];       // encoder bias staged in LDS
  alignas(16) float spad[240];      // padded buffer for sim windows
  alignas(16) int2  dpair[64];      // compacted (idx, float-bits) ascending
  alignas(16) float energyP[4][96]; // per-wave (per-ng) energy partials
  float xres[80];
  float yal[80];
  float xele[80];
  float decsrc[80];
  float zb[80];
  float energy[96];                 // 81 valid + pad (6 m-tiles of 16)
  unsigned char mp_self[256];
  unsigned char mp_src[256];
  float ext[160];
  unsigned char smask[80];
  int smask_t;
  // cross-wave scratch
  float abv[4];
  int   abi[4];
  int   wcnt[4];
  float nys;
};

// ---- wave-level primitives (64 lanes, butterfly -> all lanes hold result) ----
__device__ __forceinline__ float waveSum(float v){
  #pragma unroll
  for (int off = 32; off > 0; off >>= 1) v += __shfl_xor(v, off, 64);
  return v;
}
__device__ __forceinline__ int waveSumI(int v){
  #pragma unroll
  for (int off = 32; off > 0; off >>= 1) v += __shfl_xor(v, off, 64);
  return v;
}
__device__ __forceinline__ float waveMax(float v){
  #pragma unroll
  for (int off = 32; off > 0; off >>= 1) v = fmaxf(v, __shfl_xor(v, off, 64));
  return v;
}

// block-wide argmax, JAX tie rule (lowest index wins). Max + min-index is
// associative, so any reduction structure yields the unique answer.
__device__ __forceinline__ int blockArgMax(SM& sm, float v, int idx){
  int lane = threadIdx.x & 63, w = threadIdx.x >> 6;
  #pragma unroll
  for (int off = 32; off > 0; off >>= 1){
    float ov = __shfl_xor(v,   off, 64);
    int   oi = __shfl_xor(idx, off, 64);
    if (ov > v || (ov == v && oi < idx)){ v = ov; idx = oi; }
  }
  if (lane == 0){ sm.abv[w] = v; sm.abi[w] = idx; }
  __syncthreads();
  float bv = sm.abv[0]; int bi = sm.abi[0];
  #pragma unroll
  for (int w2 = 1; w2 < 4; w2++){
    float ov = sm.abv[w2]; int oi = sm.abi[w2];
    if (ov > bv || (ov == bv && oi < bi)){ bv = ov; bi = oi; }
  }
  __syncthreads();   // abv/abi free for reuse after this
  return bi;
}

// top-64 membership via rank over u32 float-bit keys (squares >= 0 => IEEE
// bits monotone). Exact predicate: key_i > key_j || (key_i == key_j && i<j).
// Per-wave range split: for i4 < 16w every i < tid (uniform) -> use >=;
// for i4 >= 16(w+1) every i > tid -> use >; only the 16 boundary uint4s
// need the explicit (eq && i < tid) term. rank < 64 <=> selected; keys with
// the index tiebreak form a strict total order -> exactly 64 selected.
__device__ __forceinline__ int rankTop64(SM& sm, unsigned myb, int tid, int w){
  int cnt = 0;
  const uint4* q4 = (const uint4*)sm.hkey;
  int b0 = 16 * w, b1 = b0 + 16;
  #pragma unroll 4
  for (int i4 = 0; i4 < b0; i4++){          // i < tid for all lanes: >=
    uint4 o = q4[i4];
    cnt += (o.x >= myb) ? 1 : 0;
    cnt += (o.y >= myb) ? 1 : 0;
    cnt += (o.z >= myb) ? 1 : 0;
    cnt += (o.w >= myb) ? 1 : 0;
  }
  #pragma unroll 4
  for (int i4 = b0; i4 < b1; i4++){         // boundary: exact eq/idx term
    uint4 o = q4[i4];
    int i = 4 * i4;
    cnt += ((o.x > myb) || (o.x == myb && (i    ) < tid)) ? 1 : 0;
    cnt += ((o.y > myb) || (o.y == myb && (i + 1) < tid)) ? 1 : 0;
    cnt += ((o.z > myb) || (o.z == myb && (i + 2) < tid)) ? 1 : 0;
    cnt += ((o.w > myb) || (o.w == myb && (i + 3) < tid)) ? 1 : 0;
  }
  #pragma unroll 4
  for (int i4 = b1; i4 < 64; i4++){         // i > tid for all lanes: >
    uint4 o = q4[i4];
    cnt += (o.x > myb) ? 1 : 0;
    cnt += (o.y > myb) ? 1 : 0;
    cnt += (o.z > myb) ? 1 : 0;
    cnt += (o.w > myb) ? 1 : 0;
  }
  return (cnt < 64) ? 1 : 0;
}

// Compact the exactly-64 selected (index,value) pairs into an ascending-index
// LDS list: per-wave ballot + cross-wave popcount prefix. Ascending order =>
// decode accumulation order matches the reference bit-exactly.
__device__ __forceinline__ void compactSel(SM& sm, int sel, float val){
  int tid = threadIdx.x, lane = tid & 63, w = tid >> 6;
  unsigned long long mq = __ballot(sel != 0);
  if (lane == 0) sm.wcnt[w] = __popcll(mq);
  __syncthreads();
  int base = 0;
  #pragma unroll
  for (int i = 0; i < 4; i++) base += (i < w) ? sm.wcnt[i] : 0;
  if (sel){
    unsigned long long below = (lane == 0) ? 0ull : ((~0ull) >> (64 - lane));
    int pos = base + (int)__popcll(mq & below);
    sm.dpair[pos] = make_int2(tid, __float_as_int(val));
  }
  __syncthreads();   // list ready
}

// sim_argmax: cosine sim over 159 shifts of src vs yres; thread t owns shift t.
// Per-shift fmaf chain order identical to legacy (bit-exact sims). nys is
// computed by wave 0 (legacy butterfly) only when doNy != 0 — yres is
// invariant within an iteration, so sim2 reuses sim1's nys.
__device__ __forceinline__ int simArgmax(SM& sm, const float* src, float* yal_out, int doNy){
  int tid = threadIdx.x;
  int lane = tid & 63, w = tid >> 6;
  __syncthreads();
  if (tid < 240) sm.spad[tid] = (tid >= 79 && tid < 159) ? src[tid - 79] : 0.f;
  if (doNy && w == 0){
    float yv2 = 0.f;
    for (int i = lane; i < 80; i += 64){ float yv = sm.yres[i]; yv2 = fmaf(yv, yv, yv2); }
    float ny = sqrtf(waveSum(yv2));
    if (lane == 0) sm.nys = ny;
  }
  __syncthreads();
  float nys = sm.nys;
  float bv = -INFINITY; int bi = 0;
  if (tid < 159){
    const float4* y4p = (const float4*)sm.yres;
    float num = 0.f, nx = 0.f;
    for (int w4 = 0; w4 < 20; w4++){
      float4 yy = y4p[w4];
      int wb = w4 * 4;
      float xa0 = sm.spad[tid + wb + 0];
      float xa1 = sm.spad[tid + wb + 1];
      float xa2 = sm.spad[tid + wb + 2];
      float xa3 = sm.spad[tid + wb + 3];
      num = fmaf(xa0, yy.x, num); nx = fmaf(xa0, xa0, nx);
      num = fmaf(xa1, yy.y, num); nx = fmaf(xa1, xa1, nx);
      num = fmaf(xa2, yy.z, num); nx = fmaf(xa2, xa2, nx);
      num = fmaf(xa3, yy.w, num); nx = fmaf(xa3, xa3, nx);
    }
    bv = num / (sqrtf(nx) * nys + 1e-6f);
    bi = tid;
  }
  int th = blockArgMax(sm, bv, bi);
  if (tid < 80) yal_out[tid] = sm.spad[th + tid];
  __syncthreads();
  return th;
}

// One branch: MFMA energy (split bf16; 6 single-m-tile passes with per-mt
// kt-trim — dropped products are exactly-zero A-tiles, bit-safe; wave w owns
// n-group w, partials summed in legacy ng order; A-frags read as single
// aligned b128 from rotated copies), argmax, exact fp32 row recompute
// (1 j/thread), hsr (u32-key rank), sparse decode (1 d/thread), masked loss.
template<int USE_WS>
__device__ __forceinline__ void branchCompute(
    SM& sm, const float* __restrict__ We,
    const short8* __restrict__ wsB,
    const float* __restrict__ Wdec, const float* __restrict__ bdec,
    const float* enc_in, unsigned char* mask, const float* target,
    float* dec_out, int theta, bool first, float& lossAcc)
{
  int tid = threadIdx.x;
  int lane = tid & 63, w = tid >> 6;
  int quad = lane >> 4, l15 = lane & 15;
  __syncthreads();
  {
    float v = (tid >= 80 && tid < 160) ? enc_in[tid - 80] : 0.f;
    if (tid < 240) sm.xp[tid] = v;
    unsigned bits = __float_as_uint(v);
    unsigned hi = bits >> 16;
    float hif = __uint_as_float(hi << 16);
    unsigned lo = __float_as_uint(v - hif) >> 16;
    short hs = (short)hi, ls = (short)lo;
    // rotated copies: xhr[c][i] = hi(xp[c+i]); A-frag base ≡ l15 (mod 8)
    // -> each fragment is one aligned 16B read. Values bit-identical.
    #pragma unroll
    for (int c = 0; c < 8; c++){
      int i = tid - c;
      if (i >= 0){ sm.xhr[c][i] = hs; sm.xlr[c][i] = ls; }
    }
  }
  __syncthreads();

  const floatx4 zero4 = {0.f, 0.f, 0.f, 0.f};
  const int ng = w;                  // wave w owns n-group w (4 n-tiles)
  const int c8 = l15 & 7;
  const int hb = l15 >> 3;

  #pragma unroll 1
  for (int mt = 0; mt < 6; mt++){    // one m-tile per pass (acc = 16 regs)
    // per-mt nonzero-support kt range (dropped A-tiles are exactly zero)
    const int ktlo = (mt == 0) ? 2 : ((mt <= 2) ? 1 : 0);
    const int kthi = (mt <= 1) ? 5 : ((mt <= 3) ? 4 : 3);
    floatx4 acc[4];
    #pragma unroll
    for (int nt = 0; nt < 4; nt++) acc[nt] = zero4;

    #pragma unroll 1
    for (int kt = ktlo; kt < kthi; kt++){
      // A fragments: single aligned b128 from rotated copy.
      // base = mt*16 + l15 + kt*32 + quad*8 = (l15&7) + 8*kb
      int kb = quad + 2 * mt + 4 * kt + hb;
      short8 Ah = *reinterpret_cast<const short8*>(&sm.xhr[c8][8 * kb]);
      short8 Al = *reinterpret_cast<const short8*>(&sm.xlr[c8][8 * kb]);
      // stream B per n-tile: one (Bh,Bl) pair live at a time
      #pragma unroll 1
      for (int nt = 0; nt < 4; nt++){
        short8 Bh, Bl;
        int tileIdx = kt * 16 + (ng * 4 + nt);
        if (USE_WS){
          int ti2 = (tileIdx * 64 + lane) * 2;
          Bh = wsB[ti2];
          Bl = wsB[ti2 + 1];
        } else {
          short8 bh, bl;
          int k0 = kt * 32 + quad * 8;
          int n  = (ng * 4 + nt) * 16 + l15;
          #pragma unroll
          for (int j = 0; j < 8; j++){
            float v = We[(k0 + j) * 256 + n];
            unsigned bits = __float_as_uint(v);
            unsigned hi = bits >> 16;
            float hif = __uint_as_float(hi << 16);
            unsigned lo = __float_as_uint(v - hif) >> 16;
            bh[j] = (short)hi; bl[j] = (short)lo;
          }
          Bh = bh; Bl = bl;
        }
        // per-accumulator op order unchanged vs legacy: AhBh, AlBh, AhBl
        acc[nt] = __builtin_amdgcn_mfma_f32_16x16x32_bf16(Ah, Bh, acc[nt], 0, 0, 0);
        acc[nt] = __builtin_amdgcn_mfma_f32_16x16x32_bf16(Al, Bh, acc[nt], 0, 0, 0);
        acc[nt] = __builtin_amdgcn_mfma_f32_16x16x32_bf16(Ah, Bl, acc[nt], 0, 0, 0);
      }
    }

    // epilogue: add bias, square, reduce this wave's 64 columns (l15 butterfly,
    // byte-identical to legacy per-ng computation)
    float bn[4];
    #pragma unroll
    for (int nt = 0; nt < 4; nt++) bn[nt] = sm.beL[(ng * 4 + nt) * 16 + l15];
    float er[4];
    #pragma unroll
    for (int r = 0; r < 4; r++){
      float s_ = 0.f;
      #pragma unroll
      for (int nt = 0; nt < 4; nt++){
        float hvv = acc[nt][r] + bn[nt];
        s_ = fmaf(hvv, hvv, s_);
      }
      er[r] = s_;
    }
    #pragma unroll
    for (int x2 = 1; x2 < 16; x2 <<= 1){
      #pragma unroll
      for (int r = 0; r < 4; r++) er[r] += __shfl_xor(er[r], x2, 64);
    }
    if (l15 == 0){
      #pragma unroll
      for (int r = 0; r < 4; r++)
        sm.energyP[w][mt * 16 + quad * 4 + r] = er[r];
    }
  }
  __syncthreads();
  // combine ng partials in legacy left-assoc ng order: (((ng0+ng1)+ng2)+ng3)
  if (tid < 96){
    float e = sm.energyP[0][tid];
    e += sm.energyP[1][tid];
    e += sm.energyP[2][tid];
    e += sm.energyP[3][tid];
    sm.energy[tid] = e;
  }
  __syncthreads();

  // argmax over 81 energies (padded rows >80 contain garbage — exclude them)
  float bvE = (tid < 81) ? sm.energy[tid] : -INFINITY;
  int   biE = (tid < 81) ? tid : 0;
  int ind = blockArgMax(sm, bvE, biE);

  // recompute selected row h[ind, j] EXACTLY in fp32; thread owns j = tid
  // (same per-j fmaf chain order as legacy -> bit-exact)
  int roff = 80 - ind;
  float hv = sm.beL[tid];
  #pragma unroll 8
  for (int w2 = 0; w2 < 80; w2++){
    float xv = sm.xp[80 + w2];
    hv = fmaf(xv, We[(w2 + roff) * 256 + tid], hv);
  }

  // hsr (thread's single j) — u32-key rank, bit-exact selection
  float vsq = hv * hv;
  unsigned myb = __float_as_uint(vsq);
  sm.hkey[tid] = myb;
  __syncthreads();
  int sel1 = rankTop64(sm, myb, tid, w);
  unsigned char mpv = mask[tid];
  if (first){
    mask[tid] = (unsigned char)sel1;
    compactSel(sm, sel1, hv);
  } else {
    int st = sm.smask_t;
    float interv = (float)mpv * (float)sel1;
    if (interv > 0.f && !st){
      float dd = hv - (1.f - interv);
      lossAcc += dd * dd;
    }
    float h2 = (mpv > 0) ? 0.f : hv;
    __syncthreads();               // rank1 readers done before hkey rewrite
    unsigned myb2 = __float_as_uint(h2 * h2);
    sm.hkey[tid] = myb2;
    __syncthreads();
    int sel2 = rankTop64(sm, myb2, tid, w);
    mask[tid] = (unsigned char)(mpv + (unsigned char)sel2);
    compactSel(sm, sel2, h2);
  }
  // compactSel ends with a barrier -> dpair ready

  // sparse decode over the exactly-64 selected rows (ascending idx => bit-exact):
  // ext[d] = bdec[d] + sum_{sel h asc} val_h * Wdec[h*160+d]; thread owns d = tid
  if (tid < 160){
    float a = bdec[tid];
    #pragma unroll 8
    for (int i = 0; i < 64; i++){
      int2 p = sm.dpair[i];        // block-uniform broadcast, one b64 read
      a = fmaf(__int_as_float(p.y), Wdec[p.x * 160 + tid], a);
    }
    sm.ext[tid] = a;
  }
  __syncthreads();

  float mv = fabsf((float)(theta - 79));
  bool gate = (mv > 40.0f);        // ETH
  if (tid < 80){
    float dec = sm.ext[ind + tid];
    dec_out[tid] = dec;            // residual update uses decoded output regardless of gates
    float diff = dec - target[tid];
    float l = (gate || sm.smask[tid]) ? 0.f : diff * diff;
    lossAcc += l / (mv + 1.0f);
  }
  __syncthreads();
}

__global__ void __launch_bounds__(64) zero_out_kernel(float* out){
  if (threadIdx.x == 0) out[0] = 0.f;
}

// Pre-repack We into MFMA B-fragment layout (bf16 hi and lo, interleaved):
// wsB[(tile*64+lane)*2 + {0,1}] = {hi, lo} fragment (16B each).
__global__ void __launch_bounds__(64) prep_we_kernel(
    const float* __restrict__ We, short8* __restrict__ wsB){
  int tile = blockIdx.x;
  int lane = threadIdx.x;
  int kt = tile >> 4, nt = tile & 15;
  int k0 = kt * 32 + (lane >> 4) * 8;
  int n  = nt * 16 + (lane & 15);
  short8 h, l;
  #pragma unroll
  for (int j = 0; j < 8; j++){
    float v = We[(k0 + j) * 256 + n];
    unsigned bits = __float_as_uint(v);
    unsigned hi = bits >> 16;
    float hif = __uint_as_float(hi << 16);
    unsigned lo = __float_as_uint(v - hif) >> 16;
    h[j] = (short)hi; l[j] = (short)lo;
  }
  int ti2 = (tile * 64 + lane) * 2;
  wsB[ti2]     = h;
  wsB[ti2 + 1] = l;
}

template<int USE_WS>
__global__ void __launch_bounds__(256, 8) net_kernel(
    const float* __restrict__ x,  const float* __restrict__ y,
    const float* __restrict__ We, const float* __restrict__ be,
    const float* __restrict__ Wd, const float* __restrict__ bd,
    const float* __restrict__ Wds,const float* __restrict__ bds,
    const short8* __restrict__ wsB,
    float* out)
{
  __shared__ SM sm;
  int tid = threadIdx.x;
  int lane = tid & 63, w = tid >> 6;
  int bt  = blockIdx.x;
  const float* xin = x + bt * 80;
  const float* yin = y + bt * 80;

  if (tid < 80){
    sm.xres[tid] = xin[tid];
    float yv = yin[tid];
    sm.yres[tid] = yv;
    sm.smask[tid] = (yv == 0.f) ? 1 : 0;   // seq_mask from ORIGINAL y
  }
  sm.mp_self[tid] = 0;
  sm.mp_src[tid]  = 0;
  sm.beL[tid] = be[tid];
  __syncthreads();
  if (w == 0){
    int c = 0;
    for (int i = lane; i < 80; i += 64) c += (int)sm.smask[i];
    int total = waveSumI(c);
    if (lane == 0) sm.smask_t = (total == 80) ? 1 : 0;
  }
  __syncthreads();

  float lossAcc = 0.f;

  for (int it = 0; it < 4; it++){
    bool first = (it == 0);

    // --- align x_res to y_res (computes nys for this iteration) ---
    int th1 = simArgmax(sm, sm.xres, sm.yal, 1);

    // --- attention softmax(y_al * y_res) and z = y_al * attn ---
    // order-sensitive sum: wave 0 runs the byte-identical legacy code
    if (w == 0){
      float p0 = sm.yal[lane] * sm.yres[lane];
      float p1 = (lane < 16) ? sm.yal[64 + lane] * sm.yres[64 + lane] : -INFINITY;
      float mx = waveMax(fmaxf(p0, p1));
      float e0 = expf(p0 - mx);
      float e1 = (lane < 16) ? expf(p1 - mx) : 0.f;
      float ssum = waveSum(e0 + e1);
      sm.zb[lane] = sm.yal[lane] * (e0 / ssum);
      if (lane < 16) sm.zb[64 + lane] = sm.yal[64 + lane] * (e1 / ssum);
    }
    __syncthreads();

    // --- reverse shift: x_ele[d] = z[d + 79 - theta] ---
    if (tid < 80){
      int q = tid + 79 - th1;
      sm.xele[tid] = (q >= 0 && q < 80) ? sm.zb[q] : 0.f;
    }

    // --- self branch ---
    branchCompute<USE_WS>(sm, We, wsB, Wds, bds,
                          sm.xele, sm.mp_self, sm.xres, sm.xele, th1, first, lossAcc);

    // --- re-align decoded x_ele to y_res (yres unchanged -> reuse nys) ---
    int th2 = simArgmax(sm, sm.xele, sm.yal, 0);

    // --- src branch ---
    branchCompute<USE_WS>(sm, We, wsB, Wd, bd,
                          sm.yal, sm.mp_src, sm.yres, sm.decsrc, th2, first, lossAcc);

    // --- residual updates ---
    __syncthreads();
    if (tid < 80){
      sm.xres[tid] -= sm.xele[tid];
      sm.yres[tid] -= sm.decsrc[tid];
    }
    __syncthreads();
  }

  // block loss reduction: per-wave butterfly, then fixed-order 4-way sum
  float vsum = waveSum(lossAcc);
  if (lane == 0) sm.abv[w] = vsum;
  __syncthreads();
  if (tid == 0){
    float total = ((sm.abv[0] + sm.abv[1]) + sm.abv[2]) + sm.abv[3];
    atomicAdd(out, total * 0.25f);   // mean over 4 iterations
  }
}

extern "C" void kernel_launch(void* const* d_in, const int* in_sizes, int n_in,
                              void* d_out, int out_size, void* d_ws, size_t ws_size,
                              hipStream_t stream) {
  const float* x   = (const float*)d_in[0];
  const float* y   = (const float*)d_in[1];
  const float* We  = (const float*)d_in[2];
  const float* be  = (const float*)d_in[3];
  const float* Wd  = (const float*)d_in[4];
  const float* bd  = (const float*)d_in[5];
  const float* Wds = (const float*)d_in[6];
  const float* bds = (const float*)d_in[7];
  float* out = (float*)d_out;

  // We-fragment repack buffer: 80 tiles x 64 lanes x {hi,lo} x 16B = 160 KiB
  const size_t fragCount = 80 * 64 * 2;                 // short8 elements
  const size_t fragBytes = fragCount * sizeof(short8);  // 163840 B
  int use_ws = (ws_size >= fragBytes) ? 1 : 0;
  short8* wsB = (short8*)d_ws;

  hipLaunchKernelGGL(zero_out_kernel, dim3(1), dim3(64), 0, stream, out);
  if (use_ws){
    hipLaunchKernelGGL(prep_we_kernel, dim3(80), dim3(64), 0, stream, We, wsB);
    hipLaunchKernelGGL((net_kernel<1>), dim3(NBT), dim3(256), 0, stream,
                       x, y, We, be, Wd, bd, Wds, bds, wsB, out);
  } else {
    hipLaunchKernelGGL((net_kernel<0>), dim3(NBT), dim3(256), 0, stream,
                       x, y, We, be, Wd, bd, Wds, bds, wsB, out);
  }
}

// Round 10
// 669.228 us; speedup vs baseline: 1.0142x; 1.0142x over previous
//
#include <hip/hip_runtime.h>
#include <math.h>

// Problem constants (B=8, T=256 -> 2048 independent (b,t) pipelines)
// R15: revert to the R13 champion structure (641 us; bound (256,4), 3
// mh-passes with acc[2][4], no spill) and cherry-pick R14's two good
// pieces. R14 proved the kernel is ISSUE-BOUND: VALUBusy ~60% at both 41%
// and 82% occupancy -> extra waves just time-slice the issue port, and the
// 8-waves/SIMD squeeze (32 arch VGPR) re-introduced spill (47 MB writes).
// Kept from R14 (both bit-exact):
//  - u32 rank keys (float bits of squares, monotone) with per-wave
//    range-split exact ties: halves rank's LDS broadcast traffic (was the
//    single largest LDS consumer) at equal VALU.
//  - u8 mask arrays (values are exact small ints).
#define NBT 2048

typedef __attribute__((ext_vector_type(8))) short short8;     // 8 bf16 (4 VGPRs)
typedef __attribute__((ext_vector_type(4))) float floatx4;    // MFMA C/D

struct SM {
  alignas(16) float xp[240];        // zero-padded encoder input (nonzero in [80,160))
  alignas(16) short xhr[8][264];    // rotated bf16-hi copies: xhr[c][i] = hi(xp[c+i])
  alignas(16) short xlr[8][264];    // rotated bf16-lo copies
  alignas(16) unsigned hkey[256];   // rank keys: float bits of vsq (>=0, monotone)
  alignas(16) float yres[80];
  alignas(16) float beL[256];       // encoder bias staged in LDS
  alignas(16) float spad[240];      // padded buffer for sim windows
  alignas(16) int2  dpair[64];      // compacted (idx, float-bits) ascending
  alignas(16) float energyP[4][96]; // per-wave (per-ng) energy partials
  float xres[80];
  float yal[80];
  float xele[80];
  float decsrc[80];
  float zb[80];
  float energy[96];                 // 81 valid + pad (6 m-tiles of 16)
  unsigned char mp_self[256];
  unsigned char mp_src[256];
  float ext[160];
  unsigned char smask[80];
  int smask_t;
  // cross-wave scratch
  float abv[4];
  int   abi[4];
  int   wcnt[4];
  float nys;
};

// ---- wave-level primitives (64 lanes, butterfly -> all lanes hold result) ----
__device__ __forceinline__ float waveSum(float v){
  #pragma unroll
  for (int off = 32; off > 0; off >>= 1) v += __shfl_xor(v, off, 64);
  return v;
}
__device__ __forceinline__ int waveSumI(int v){
  #pragma unroll
  for (int off = 32; off > 0; off >>= 1) v += __shfl_xor(v, off, 64);
  return v;
}
__device__ __forceinline__ float waveMax(float v){
  #pragma unroll
  for (int off = 32; off > 0; off >>= 1) v = fmaxf(v, __shfl_xor(v, off, 64));
  return v;
}

// block-wide argmax, JAX tie rule (lowest index wins). Max + min-index is
// associative, so any reduction structure yields the unique answer.
__device__ __forceinline__ int blockArgMax(SM& sm, float v, int idx){
  int lane = threadIdx.x & 63, w = threadIdx.x >> 6;
  #pragma unroll
  for (int off = 32; off > 0; off >>= 1){
    float ov = __shfl_xor(v,   off, 64);
    int   oi = __shfl_xor(idx, off, 64);
    if (ov > v || (ov == v && oi < idx)){ v = ov; idx = oi; }
  }
  if (lane == 0){ sm.abv[w] = v; sm.abi[w] = idx; }
  __syncthreads();
  float bv = sm.abv[0]; int bi = sm.abi[0];
  #pragma unroll
  for (int w2 = 1; w2 < 4; w2++){
    float ov = sm.abv[w2]; int oi = sm.abi[w2];
    if (ov > bv || (ov == bv && oi < bi)){ bv = ov; bi = oi; }
  }
  __syncthreads();   // abv/abi free for reuse after this
  return bi;
}

// top-64 membership via rank over u32 float-bit keys (squares >= 0 => IEEE
// bits monotone). Exact predicate: key_i > key_j || (key_i == key_j && i<j).
// Per-wave range split: for i4 < 16w every i < tid (uniform) -> use >=;
// for i4 >= 16(w+1) every i > tid -> use >; only the 16 boundary uint4s
// need the explicit (eq && i < tid) term. rank < 64 <=> selected; keys with
// the index tiebreak form a strict total order -> exactly 64 selected.
__device__ __forceinline__ int rankTop64(SM& sm, unsigned myb, int tid, int w){
  int cnt = 0;
  const uint4* q4 = (const uint4*)sm.hkey;
  int b0 = 16 * w, b1 = b0 + 16;
  #pragma unroll 4
  for (int i4 = 0; i4 < b0; i4++){          // i < tid for all lanes: >=
    uint4 o = q4[i4];
    cnt += (o.x >= myb) ? 1 : 0;
    cnt += (o.y >= myb) ? 1 : 0;
    cnt += (o.z >= myb) ? 1 : 0;
    cnt += (o.w >= myb) ? 1 : 0;
  }
  #pragma unroll 4
  for (int i4 = b0; i4 < b1; i4++){         // boundary: exact eq/idx term
    uint4 o = q4[i4];
    int i = 4 * i4;
    cnt += ((o.x > myb) || (o.x == myb && (i    ) < tid)) ? 1 : 0;
    cnt += ((o.y > myb) || (o.y == myb && (i + 1) < tid)) ? 1 : 0;
    cnt += ((o.z > myb) || (o.z == myb && (i + 2) < tid)) ? 1 : 0;
    cnt += ((o.w > myb) || (o.w == myb && (i + 3) < tid)) ? 1 : 0;
  }
  #pragma unroll 4
  for (int i4 = b1; i4 < 64; i4++){         // i > tid for all lanes: >
    uint4 o = q4[i4];
    cnt += (o.x > myb) ? 1 : 0;
    cnt += (o.y > myb) ? 1 : 0;
    cnt += (o.z > myb) ? 1 : 0;
    cnt += (o.w > myb) ? 1 : 0;
  }
  return (cnt < 64) ? 1 : 0;
}

// Compact the exactly-64 selected (index,value) pairs into an ascending-index
// LDS list: per-wave ballot + cross-wave popcount prefix. Ascending order =>
// decode accumulation order matches the reference bit-exactly.
__device__ __forceinline__ void compactSel(SM& sm, int sel, float val){
  int tid = threadIdx.x, lane = tid & 63, w = tid >> 6;
  unsigned long long mq = __ballot(sel != 0);
  if (lane == 0) sm.wcnt[w] = __popcll(mq);
  __syncthreads();
  int base = 0;
  #pragma unroll
  for (int i = 0; i < 4; i++) base += (i < w) ? sm.wcnt[i] : 0;
  if (sel){
    unsigned long long below = (lane == 0) ? 0ull : ((~0ull) >> (64 - lane));
    int pos = base + (int)__popcll(mq & below);
    sm.dpair[pos] = make_int2(tid, __float_as_int(val));
  }
  __syncthreads();   // list ready
}

// sim_argmax: cosine sim over 159 shifts of src vs yres; thread t owns shift t.
// Per-shift fmaf chain order identical to legacy (bit-exact sims). nys is
// computed by wave 0 (legacy butterfly) only when doNy != 0 — yres is
// invariant within an iteration, so sim2 reuses sim1's nys.
__device__ __forceinline__ int simArgmax(SM& sm, const float* src, float* yal_out, int doNy){
  int tid = threadIdx.x;
  int lane = tid & 63, w = tid >> 6;
  __syncthreads();
  if (tid < 240) sm.spad[tid] = (tid >= 79 && tid < 159) ? src[tid - 79] : 0.f;
  if (doNy && w == 0){
    float yv2 = 0.f;
    for (int i = lane; i < 80; i += 64){ float yv = sm.yres[i]; yv2 = fmaf(yv, yv, yv2); }
    float ny = sqrtf(waveSum(yv2));
    if (lane == 0) sm.nys = ny;
  }
  __syncthreads();
  float nys = sm.nys;
  float bv = -INFINITY; int bi = 0;
  if (tid < 159){
    const float4* y4p = (const float4*)sm.yres;
    float num = 0.f, nx = 0.f;
    for (int w4 = 0; w4 < 20; w4++){
      float4 yy = y4p[w4];
      int wb = w4 * 4;
      float xa0 = sm.spad[tid + wb + 0];
      float xa1 = sm.spad[tid + wb + 1];
      float xa2 = sm.spad[tid + wb + 2];
      float xa3 = sm.spad[tid + wb + 3];
      num = fmaf(xa0, yy.x, num); nx = fmaf(xa0, xa0, nx);
      num = fmaf(xa1, yy.y, num); nx = fmaf(xa1, xa1, nx);
      num = fmaf(xa2, yy.z, num); nx = fmaf(xa2, xa2, nx);
      num = fmaf(xa3, yy.w, num); nx = fmaf(xa3, xa3, nx);
    }
    bv = num / (sqrtf(nx) * nys + 1e-6f);
    bi = tid;
  }
  int th = blockArgMax(sm, bv, bi);
  if (tid < 80) yal_out[tid] = sm.spad[th + tid];
  __syncthreads();
  return th;
}

// One branch: MFMA energy (split bf16, kt-trimmed — bit-safe; wave w owns
// n-group w, partials summed in legacy ng order; A-frags read as single
// aligned b128 from rotated copies; B-frags streamed per n-tile), argmax,
// exact fp32 row recompute (1 j/thread), hsr (u32-key rank), sparse decode
// (1 d/thread), masked loss.
template<int USE_WS>
__device__ __forceinline__ void branchCompute(
    SM& sm, const float* __restrict__ We,
    const short8* __restrict__ wsB,
    const float* __restrict__ Wdec, const float* __restrict__ bdec,
    const float* enc_in, unsigned char* mask, const float* target,
    float* dec_out, int theta, bool first, float& lossAcc)
{
  int tid = threadIdx.x;
  int lane = tid & 63, w = tid >> 6;
  int quad = lane >> 4, l15 = lane & 15;
  __syncthreads();
  {
    float v = (tid >= 80 && tid < 160) ? enc_in[tid - 80] : 0.f;
    if (tid < 240) sm.xp[tid] = v;
    unsigned bits = __float_as_uint(v);
    unsigned hi = bits >> 16;
    float hif = __uint_as_float(hi << 16);
    unsigned lo = __float_as_uint(v - hif) >> 16;
    short hs = (short)hi, ls = (short)lo;
    // rotated copies: xhr[c][i] = hi(xp[c+i]); A-frag base ≡ l15 (mod 8)
    // -> each fragment is one aligned 16B read. Values bit-identical.
    #pragma unroll
    for (int c = 0; c < 8; c++){
      int i = tid - c;
      if (i >= 0){ sm.xhr[c][i] = hs; sm.xlr[c][i] = ls; }
    }
  }
  __syncthreads();

  const floatx4 zero4 = {0.f, 0.f, 0.f, 0.f};
  const int ng = w;                  // wave w owns n-group w (4 n-tiles)
  const int c8 = l15 & 7;
  const int hb = l15 >> 3;

  #pragma unroll 1
  for (int mh = 0; mh < 3; mh++){    // 2 m-tiles per pass (acc = 32 regs)
    int ktlo = (mh == 0) ? 1 : 0;    // nonzero-support kt range for these m rows
    int kthi = 5 - mh;               // (skipped products are exactly 0 -> bit-safe)
    floatx4 acc[2][4];
    #pragma unroll
    for (int m2 = 0; m2 < 2; m2++)
      #pragma unroll
      for (int nt = 0; nt < 4; nt++) acc[m2][nt] = zero4;

    #pragma unroll 1
    for (int kt = ktlo; kt < kthi; kt++){
      // A fragments for this kt, both m-tiles: single aligned b128 each.
      // base = mt*16 + l15 + kt*32 + quad*8 = (l15&7) + 8*kb
      short8 Ah[2], Al[2];
      #pragma unroll
      for (int m2 = 0; m2 < 2; m2++){
        int mt = mh * 2 + m2;
        int kb = quad + 2 * mt + 4 * kt + hb;
        Ah[m2] = *reinterpret_cast<const short8*>(&sm.xhr[c8][8 * kb]);
        Al[m2] = *reinterpret_cast<const short8*>(&sm.xlr[c8][8 * kb]);
      }
      // stream B per n-tile: only one (Bh,Bl) pair live at a time (x2 unroll)
      #pragma unroll 2
      for (int nt = 0; nt < 4; nt++){
        short8 Bh, Bl;
        int tileIdx = kt * 16 + (ng * 4 + nt);
        if (USE_WS){
          int ti2 = (tileIdx * 64 + lane) * 2;
          Bh = wsB[ti2];
          Bl = wsB[ti2 + 1];
        } else {
          short8 bh, bl;
          int k0 = kt * 32 + quad * 8;
          int n  = (ng * 4 + nt) * 16 + l15;
          #pragma unroll
          for (int j = 0; j < 8; j++){
            float v = We[(k0 + j) * 256 + n];
            unsigned bits = __float_as_uint(v);
            unsigned hi = bits >> 16;
            float hif = __uint_as_float(hi << 16);
            unsigned lo = __float_as_uint(v - hif) >> 16;
            bh[j] = (short)hi; bl[j] = (short)lo;
          }
          Bh = bh; Bl = bl;
        }
        // per-accumulator op order unchanged vs legacy: AhBh, AlBh, AhBl
        acc[0][nt] = __builtin_amdgcn_mfma_f32_16x16x32_bf16(Ah[0], Bh, acc[0][nt], 0, 0, 0);
        acc[0][nt] = __builtin_amdgcn_mfma_f32_16x16x32_bf16(Al[0], Bh, acc[0][nt], 0, 0, 0);
        acc[0][nt] = __builtin_amdgcn_mfma_f32_16x16x32_bf16(Ah[0], Bl, acc[0][nt], 0, 0, 0);
        acc[1][nt] = __builtin_amdgcn_mfma_f32_16x16x32_bf16(Ah[1], Bh, acc[1][nt], 0, 0, 0);
        acc[1][nt] = __builtin_amdgcn_mfma_f32_16x16x32_bf16(Al[1], Bh, acc[1][nt], 0, 0, 0);
        acc[1][nt] = __builtin_amdgcn_mfma_f32_16x16x32_bf16(Ah[1], Bl, acc[1][nt], 0, 0, 0);
      }
    }

    // epilogue: add bias, square, reduce this wave's 64 columns (l15 butterfly,
    // byte-identical to legacy per-ng computation)
    float bn[4];
    #pragma unroll
    for (int nt = 0; nt < 4; nt++) bn[nt] = sm.beL[(ng * 4 + nt) * 16 + l15];
    #pragma unroll
    for (int m2 = 0; m2 < 2; m2++){
      int mt = mh * 2 + m2;
      float er[4];
      #pragma unroll
      for (int r = 0; r < 4; r++){
        float s_ = 0.f;
        #pragma unroll
        for (int nt = 0; nt < 4; nt++){
          float hvv = acc[m2][nt][r] + bn[nt];
          s_ = fmaf(hvv, hvv, s_);
        }
        er[r] = s_;
      }
      #pragma unroll
      for (int x2 = 1; x2 < 16; x2 <<= 1){
        #pragma unroll
        for (int r = 0; r < 4; r++) er[r] += __shfl_xor(er[r], x2, 64);
      }
      if (l15 == 0){
        #pragma unroll
        for (int r = 0; r < 4; r++)
          sm.energyP[w][mt * 16 + quad * 4 + r] = er[r];
      }
    }
  }
  __syncthreads();
  // combine ng partials in legacy left-assoc ng order: (((ng0+ng1)+ng2)+ng3)
  if (tid < 96){
    float e = sm.energyP[0][tid];
    e += sm.energyP[1][tid];
    e += sm.energyP[2][tid];
    e += sm.energyP[3][tid];
    sm.energy[tid] = e;
  }
  __syncthreads();

  // argmax over 81 energies (padded rows >80 contain garbage — exclude them)
  float bvE = (tid < 81) ? sm.energy[tid] : -INFINITY;
  int   biE = (tid < 81) ? tid : 0;
  int ind = blockArgMax(sm, bvE, biE);

  // recompute selected row h[ind, j] EXACTLY in fp32; thread owns j = tid
  // (same per-j fmaf chain order as legacy -> bit-exact)
  int roff = 80 - ind;
  float hv = sm.beL[tid];
  #pragma unroll 8
  for (int w2 = 0; w2 < 80; w2++){
    float xv = sm.xp[80 + w2];
    hv = fmaf(xv, We[(w2 + roff) * 256 + tid], hv);
  }

  // hsr (thread's single j) — u32-key rank, bit-exact selection
  float vsq = hv * hv;
  unsigned myb = __float_as_uint(vsq);
  sm.hkey[tid] = myb;
  __syncthreads();
  int sel1 = rankTop64(sm, myb, tid, w);
  unsigned char mpv = mask[tid];
  if (first){
    mask[tid] = (unsigned char)sel1;
    compactSel(sm, sel1, hv);
  } else {
    int st = sm.smask_t;
    float interv = (float)mpv * (float)sel1;
    if (interv > 0.f && !st){
      float dd = hv - (1.f - interv);
      lossAcc += dd * dd;
    }
    float h2 = (mpv > 0) ? 0.f : hv;
    __syncthreads();               // rank1 readers done before hkey rewrite
    unsigned myb2 = __float_as_uint(h2 * h2);
    sm.hkey[tid] = myb2;
    __syncthreads();
    int sel2 = rankTop64(sm, myb2, tid, w);
    mask[tid] = (unsigned char)(mpv + (unsigned char)sel2);
    compactSel(sm, sel2, h2);
  }
  // compactSel ends with a barrier -> dpair ready

  // sparse decode over the exactly-64 selected rows (ascending idx => bit-exact):
  // ext[d] = bdec[d] + sum_{sel h asc} val_h * Wdec[h*160+d]; thread owns d = tid
  if (tid < 160){
    float a = bdec[tid];
    #pragma unroll 8
    for (int i = 0; i < 64; i++){
      int2 p = sm.dpair[i];        // block-uniform broadcast, one b64 read
      a = fmaf(__int_as_float(p.y), Wdec[p.x * 160 + tid], a);
    }
    sm.ext[tid] = a;
  }
  __syncthreads();

  float mv = fabsf((float)(theta - 79));
  bool gate = (mv > 40.0f);        // ETH
  if (tid < 80){
    float dec = sm.ext[ind + tid];
    dec_out[tid] = dec;            // residual update uses decoded output regardless of gates
    float diff = dec - target[tid];
    float l = (gate || sm.smask[tid]) ? 0.f : diff * diff;
    lossAcc += l / (mv + 1.0f);
  }
  __syncthreads();
}

__global__ void __launch_bounds__(64) zero_out_kernel(float* out){
  if (threadIdx.x == 0) out[0] = 0.f;
}

// Pre-repack We into MFMA B-fragment layout (bf16 hi and lo, interleaved):
// wsB[(tile*64+lane)*2 + {0,1}] = {hi, lo} fragment (16B each).
__global__ void __launch_bounds__(64) prep_we_kernel(
    const float* __restrict__ We, short8* __restrict__ wsB){
  int tile = blockIdx.x;
  int lane = threadIdx.x;
  int kt = tile >> 4, nt = tile & 15;
  int k0 = kt * 32 + (lane >> 4) * 8;
  int n  = nt * 16 + (lane & 15);
  short8 h, l;
  #pragma unroll
  for (int j = 0; j < 8; j++){
    float v = We[(k0 + j) * 256 + n];
    unsigned bits = __float_as_uint(v);
    unsigned hi = bits >> 16;
    float hif = __uint_as_float(hi << 16);
    unsigned lo = __float_as_uint(v - hif) >> 16;
    h[j] = (short)hi; l[j] = (short)lo;
  }
  int ti2 = (tile * 64 + lane) * 2;
  wsB[ti2]     = h;
  wsB[ti2 + 1] = l;
}

template<int USE_WS>
__global__ void __launch_bounds__(256, 4) net_kernel(
    const float* __restrict__ x,  const float* __restrict__ y,
    const float* __restrict__ We, const float* __restrict__ be,
    const float* __restrict__ Wd, const float* __restrict__ bd,
    const float* __restrict__ Wds,const float* __restrict__ bds,
    const short8* __restrict__ wsB,
    float* out)
{
  __shared__ SM sm;
  int tid = threadIdx.x;
  int lane = tid & 63, w = tid >> 6;
  int bt  = blockIdx.x;
  const float* xin = x + bt * 80;
  const float* yin = y + bt * 80;

  if (tid < 80){
    sm.xres[tid] = xin[tid];
    float yv = yin[tid];
    sm.yres[tid] = yv;
    sm.smask[tid] = (yv == 0.f) ? 1 : 0;   // seq_mask from ORIGINAL y
  }
  sm.mp_self[tid] = 0;
  sm.mp_src[tid]  = 0;
  sm.beL[tid] = be[tid];
  __syncthreads();
  if (w == 0){
    int c = 0;
    for (int i = lane; i < 80; i += 64) c += (int)sm.smask[i];
    int total = waveSumI(c);
    if (lane == 0) sm.smask_t = (total == 80) ? 1 : 0;
  }
  __syncthreads();

  float lossAcc = 0.f;

  for (int it = 0; it < 4; it++){
    bool first = (it == 0);

    // --- align x_res to y_res (computes nys for this iteration) ---
    int th1 = simArgmax(sm, sm.xres, sm.yal, 1);

    // --- attention softmax(y_al * y_res) and z = y_al * attn ---
    // order-sensitive sum: wave 0 runs the byte-identical legacy code
    if (w == 0){
      float p0 = sm.yal[lane] * sm.yres[lane];
      float p1 = (lane < 16) ? sm.yal[64 + lane] * sm.yres[64 + lane] : -INFINITY;
      float mx = waveMax(fmaxf(p0, p1));
      float e0 = expf(p0 - mx);
      float e1 = (lane < 16) ? expf(p1 - mx) : 0.f;
      float ssum = waveSum(e0 + e1);
      sm.zb[lane] = sm.yal[lane] * (e0 / ssum);
      if (lane < 16) sm.zb[64 + lane] = sm.yal[64 + lane] * (e1 / ssum);
    }
    __syncthreads();

    // --- reverse shift: x_ele[d] = z[d + 79 - theta] ---
    if (tid < 80){
      int q = tid + 79 - th1;
      sm.xele[tid] = (q >= 0 && q < 80) ? sm.zb[q] : 0.f;
    }

    // --- self branch ---
    branchCompute<USE_WS>(sm, We, wsB, Wds, bds,
                          sm.xele, sm.mp_self, sm.xres, sm.xele, th1, first, lossAcc);

    // --- re-align decoded x_ele to y_res (yres unchanged -> reuse nys) ---
    int th2 = simArgmax(sm, sm.xele, sm.yal, 0);

    // --- src branch ---
    branchCompute<USE_WS>(sm, We, wsB, Wd, bd,
                          sm.yal, sm.mp_src, sm.yres, sm.decsrc, th2, first, lossAcc);

    // --- residual updates ---
    __syncthreads();
    if (tid < 80){
      sm.xres[tid] -= sm.xele[tid];
      sm.yres[tid] -= sm.decsrc[tid];
    }
    __syncthreads();
  }

  // block loss reduction: per-wave butterfly, then fixed-order 4-way sum
  float vsum = waveSum(lossAcc);
  if (lane == 0) sm.abv[w] = vsum;
  __syncthreads();
  if (tid == 0){
    float total = ((sm.abv[0] + sm.abv[1]) + sm.abv[2]) + sm.abv[3];
    atomicAdd(out, total * 0.25f);   // mean over 4 iterations
  }
}

extern "C" void kernel_launch(void* const* d_in, const int* in_sizes, int n_in,
                              void* d_out, int out_size, void* d_ws, size_t ws_size,
                              hipStream_t stream) {
  const float* x   = (const float*)d_in[0];
  const float* y   = (const float*)d_in[1];
  const float* We  = (const float*)d_in[2];
  const float* be  = (const float*)d_in[3];
  const float* Wd  = (const float*)d_in[4];
  const float* bd  = (const float*)d_in[5];
  const float* Wds = (const float*)d_in[6];
  const float* bds = (const float*)d_in[7];
  float* out = (float*)d_out;

  // We-fragment repack buffer: 80 tiles x 64 lanes x {hi,lo} x 16B = 160 KiB
  const size_t fragCount = 80 * 64 * 2;                 // short8 elements
  const size_t fragBytes = fragCount * sizeof(short8);  // 163840 B
  int use_ws = (ws_size >= fragBytes) ? 1 : 0;
  short8* wsB = (short8*)d_ws;

  hipLaunchKernelGGL(zero_out_kernel, dim3(1), dim3(64), 0, stream, out);
  if (use_ws){
    hipLaunchKernelGGL(prep_we_kernel, dim3(80), dim3(64), 0, stream, We, wsB);
    hipLaunchKernelGGL((net_kernel<1>), dim3(NBT), dim3(256), 0, stream,
                       x, y, We, be, Wd, bd, Wds, bds, wsB, out);
  } else {
    hipLaunchKernelGGL((net_kernel<0>), dim3(NBT), dim3(256), 0, stream,
                       x, y, We, be, Wd, bd, Wds, bds, wsB, out);
  }
}

// Round 11
// 633.044 us; speedup vs baseline: 1.0721x; 1.0572x over previous
//
#include <hip/hip_runtime.h>
#include <math.h>

// Problem constants (B=8, T=256 -> 2048 independent (b,t) pipelines)
// R16: revert R15's rank regression, keep its good pieces, add two small
// exact issue-slot cuts. R15 (669 us) showed the u32 range-split rank has
// RUNTIME loop bounds (b0=16*w) -> three partial-unroll loops + loop
// control on an issue-bound kernel = net loss vs the u64 fixed-128 loop
// (R13, 641 us). Changes vs R15:
//  - rank: back to u64 keys (bits<<8)|(255-j), single fixed-count loop.
//  - sim: 4 rotated spad copies -> 20 aligned ds_read_b128 per call
//    instead of 80 unaligned scalar reads (same fmaf order, bit-exact;
//    4-lane broadcast groups -> conflict-free).
//  - decode: dpair.x stores idx*640 (byte offset); per-thread base pointer
//    removes the per-iteration multiply.
//  - kept: u8 masks, dpair, rotated A-copies, nys hoist, bound (256,4).
#define NBT 2048

typedef __attribute__((ext_vector_type(8))) short short8;     // 8 bf16 (4 VGPRs)
typedef __attribute__((ext_vector_type(4))) float floatx4;    // MFMA C/D

struct SM {
  alignas(16) float xp[240];        // zero-padded encoder input (nonzero in [80,160))
  alignas(16) short xhr[8][264];    // rotated bf16-hi copies: xhr[c][i] = hi(xp[c+i])
  alignas(16) short xlr[8][264];    // rotated bf16-lo copies
  alignas(16) unsigned long long hkey[256]; // rank keys: (bits(vsq)<<8)|(255-j)
  alignas(16) float yres[80];
  alignas(16) float beL[256];       // encoder bias staged in LDS
  alignas(16) float spadr[4][244];  // rotated sim windows: spadr[c][i] = spad[i+c]
  alignas(16) int2  dpair[64];      // compacted (byte-offset idx*640, float-bits)
  alignas(16) float energyP[4][96]; // per-wave (per-ng) energy partials
  float xres[80];
  float yal[80];
  float xele[80];
  float decsrc[80];
  float zb[80];
  float energy[96];                 // 81 valid + pad (6 m-tiles of 16)
  unsigned char mp_self[256];
  unsigned char mp_src[256];
  float ext[160];
  unsigned char smask[80];
  int smask_t;
  // cross-wave scratch
  float abv[4];
  int   abi[4];
  int   wcnt[4];
  float nys;
};

// ---- wave-level primitives (64 lanes, butterfly -> all lanes hold result) ----
__device__ __forceinline__ float waveSum(float v){
  #pragma unroll
  for (int off = 32; off > 0; off >>= 1) v += __shfl_xor(v, off, 64);
  return v;
}
__device__ __forceinline__ int waveSumI(int v){
  #pragma unroll
  for (int off = 32; off > 0; off >>= 1) v += __shfl_xor(v, off, 64);
  return v;
}
__device__ __forceinline__ float waveMax(float v){
  #pragma unroll
  for (int off = 32; off > 0; off >>= 1) v = fmaxf(v, __shfl_xor(v, off, 64));
  return v;
}

// block-wide argmax, JAX tie rule (lowest index wins). Max + min-index is
// associative, so any reduction structure yields the unique answer.
__device__ __forceinline__ int blockArgMax(SM& sm, float v, int idx){
  int lane = threadIdx.x & 63, w = threadIdx.x >> 6;
  #pragma unroll
  for (int off = 32; off > 0; off >>= 1){
    float ov = __shfl_xor(v,   off, 64);
    int   oi = __shfl_xor(idx, off, 64);
    if (ov > v || (ov == v && oi < idx)){ v = ov; idx = oi; }
  }
  if (lane == 0){ sm.abv[w] = v; sm.abi[w] = idx; }
  __syncthreads();
  float bv = sm.abv[0]; int bi = sm.abi[0];
  #pragma unroll
  for (int w2 = 1; w2 < 4; w2++){
    float ov = sm.abv[w2]; int oi = sm.abi[w2];
    if (ov > bv || (ov == bv && oi < bi)){ bv = ov; bi = oi; }
  }
  __syncthreads();   // abv/abi free for reuse after this
  return bi;
}

// top-64 membership via rank over u64 integer keys. vsq >= 0 (squares) =>
// IEEE bits monotone => key_i > key_j <=> v_i > v_j || (v_i==v_j && i<j).
// rank = #{key_i > key_j}; selected iff rank < 64. Keys unique by index =>
// exactly 64 selected. hkey reads are block-uniform -> LDS broadcast.
// Fixed 128-iteration loop: fully unrollable, 2 VALU/element.
__device__ __forceinline__ int rankTop64(SM& sm, unsigned long long mykey){
  int cnt = 0;
  const ulonglong2* q2 = (const ulonglong2*)sm.hkey;
  #pragma unroll 8
  for (int i2 = 0; i2 < 128; i2++){
    ulonglong2 o = q2[i2];
    cnt += (o.x > mykey) ? 1 : 0;
    cnt += (o.y > mykey) ? 1 : 0;
  }
  return (cnt < 64) ? 1 : 0;
}
__device__ __forceinline__ unsigned long long rankKey(float vsq, int j){
  return (((unsigned long long)__float_as_uint(vsq)) << 8)
       | (unsigned long long)(255 - j);
}

// Compact the exactly-64 selected (offset,value) pairs into an ascending-index
// LDS list: per-wave ballot + cross-wave popcount prefix. Ascending order =>
// decode accumulation order matches the reference bit-exactly. The stored
// .x is the PRE-SCALED byte offset idx*640 (Wdec rows are 160 floats).
__device__ __forceinline__ void compactSel(SM& sm, int sel, float val){
  int tid = threadIdx.x, lane = tid & 63, w = tid >> 6;
  unsigned long long mq = __ballot(sel != 0);
  if (lane == 0) sm.wcnt[w] = __popcll(mq);
  __syncthreads();
  int base = 0;
  #pragma unroll
  for (int i = 0; i < 4; i++) base += (i < w) ? sm.wcnt[i] : 0;
  if (sel){
    unsigned long long below = (lane == 0) ? 0ull : ((~0ull) >> (64 - lane));
    int pos = base + (int)__popcll(mq & below);
    sm.dpair[pos] = make_int2(tid * 640, __float_as_int(val));
  }
  __syncthreads();   // list ready
}

// sim_argmax: cosine sim over 159 shifts of src vs yres; thread t owns shift t.
// Per-shift fmaf chain order identical to legacy (bit-exact sims). spad is
// held as 4 rotated copies so each thread's 4-wide window read is one
// aligned ds_read_b128 (values bit-identical). nys computed by wave 0
// (legacy butterfly) only when doNy != 0 — yres invariant within iteration.
__device__ __forceinline__ int simArgmax(SM& sm, const float* src, float* yal_out, int doNy){
  int tid = threadIdx.x;
  int lane = tid & 63, w = tid >> 6;
  __syncthreads();
  {
    float v = (tid >= 79 && tid < 159) ? src[tid - 79] : 0.f;
    #pragma unroll
    for (int c = 0; c < 4; c++){
      int i = tid - c;
      if (i >= 0 && i < 240){ sm.spadr[c][i] = v; }
    }
  }
  if (doNy && w == 0){
    float yv2 = 0.f;
    for (int i = lane; i < 80; i += 64){ float yv = sm.yres[i]; yv2 = fmaf(yv, yv, yv2); }
    float ny = sqrtf(waveSum(yv2));
    if (lane == 0) sm.nys = ny;
  }
  __syncthreads();
  float nys = sm.nys;
  float bv = -INFINITY; int bi = 0;
  if (tid < 159){
    const int c = tid & 3;
    const float4* xr = (const float4*)&sm.spadr[c][tid - c];  // 16B aligned
    const float4* y4p = (const float4*)sm.yres;
    float num = 0.f, nx = 0.f;
    for (int w4 = 0; w4 < 20; w4++){
      float4 yy = y4p[w4];
      float4 xa = xr[w4];          // = spad[tid+4w4 .. +3], bit-identical
      num = fmaf(xa.x, yy.x, num); nx = fmaf(xa.x, xa.x, nx);
      num = fmaf(xa.y, yy.y, num); nx = fmaf(xa.y, xa.y, nx);
      num = fmaf(xa.z, yy.z, num); nx = fmaf(xa.z, xa.z, nx);
      num = fmaf(xa.w, yy.w, num); nx = fmaf(xa.w, xa.w, nx);
    }
    bv = num / (sqrtf(nx) * nys + 1e-6f);
    bi = tid;
  }
  int th = blockArgMax(sm, bv, bi);
  if (tid < 80) yal_out[tid] = sm.spadr[0][th + tid];
  __syncthreads();
  return th;
}

// One branch: MFMA energy (split bf16, kt-trimmed — bit-safe; wave w owns
// n-group w, partials summed in legacy ng order; A-frags read as single
// aligned b128 from rotated copies; B-frags streamed per n-tile), argmax,
// exact fp32 row recompute (1 j/thread), hsr (u64-key rank), sparse decode
// (1 d/thread), masked loss.
template<int USE_WS>
__device__ __forceinline__ void branchCompute(
    SM& sm, const float* __restrict__ We,
    const short8* __restrict__ wsB,
    const float* __restrict__ Wdec, const float* __restrict__ bdec,
    const float* enc_in, unsigned char* mask, const float* target,
    float* dec_out, int theta, bool first, float& lossAcc)
{
  int tid = threadIdx.x;
  int lane = tid & 63, w = tid >> 6;
  int quad = lane >> 4, l15 = lane & 15;
  __syncthreads();
  {
    float v = (tid >= 80 && tid < 160) ? enc_in[tid - 80] : 0.f;
    if (tid < 240) sm.xp[tid] = v;
    unsigned bits = __float_as_uint(v);
    unsigned hi = bits >> 16;
    float hif = __uint_as_float(hi << 16);
    unsigned lo = __float_as_uint(v - hif) >> 16;
    short hs = (short)hi, ls = (short)lo;
    // rotated copies: xhr[c][i] = hi(xp[c+i]); A-frag base ≡ l15 (mod 8)
    // -> each fragment is one aligned 16B read. Values bit-identical.
    #pragma unroll
    for (int c = 0; c < 8; c++){
      int i = tid - c;
      if (i >= 0){ sm.xhr[c][i] = hs; sm.xlr[c][i] = ls; }
    }
  }
  __syncthreads();

  const floatx4 zero4 = {0.f, 0.f, 0.f, 0.f};
  const int ng = w;                  // wave w owns n-group w (4 n-tiles)
  const int c8 = l15 & 7;
  const int hb = l15 >> 3;

  #pragma unroll 1
  for (int mh = 0; mh < 3; mh++){    // 2 m-tiles per pass (acc = 32 regs)
    int ktlo = (mh == 0) ? 1 : 0;    // nonzero-support kt range for these m rows
    int kthi = 5 - mh;               // (skipped products are exactly 0 -> bit-safe)
    floatx4 acc[2][4];
    #pragma unroll
    for (int m2 = 0; m2 < 2; m2++)
      #pragma unroll
      for (int nt = 0; nt < 4; nt++) acc[m2][nt] = zero4;

    #pragma unroll 1
    for (int kt = ktlo; kt < kthi; kt++){
      // A fragments for this kt, both m-tiles: single aligned b128 each.
      // base = mt*16 + l15 + kt*32 + quad*8 = (l15&7) + 8*kb
      short8 Ah[2], Al[2];
      #pragma unroll
      for (int m2 = 0; m2 < 2; m2++){
        int mt = mh * 2 + m2;
        int kb = quad + 2 * mt + 4 * kt + hb;
        Ah[m2] = *reinterpret_cast<const short8*>(&sm.xhr[c8][8 * kb]);
        Al[m2] = *reinterpret_cast<const short8*>(&sm.xlr[c8][8 * kb]);
      }
      // stream B per n-tile: only one (Bh,Bl) pair live at a time (x2 unroll)
      #pragma unroll 2
      for (int nt = 0; nt < 4; nt++){
        short8 Bh, Bl;
        int tileIdx = kt * 16 + (ng * 4 + nt);
        if (USE_WS){
          int ti2 = (tileIdx * 64 + lane) * 2;
          Bh = wsB[ti2];
          Bl = wsB[ti2 + 1];
        } else {
          short8 bh, bl;
          int k0 = kt * 32 + quad * 8;
          int n  = (ng * 4 + nt) * 16 + l15;
          #pragma unroll
          for (int j = 0; j < 8; j++){
            float v = We[(k0 + j) * 256 + n];
            unsigned bits = __float_as_uint(v);
            unsigned hi = bits >> 16;
            float hif = __uint_as_float(hi << 16);
            unsigned lo = __float_as_uint(v - hif) >> 16;
            bh[j] = (short)hi; bl[j] = (short)lo;
          }
          Bh = bh; Bl = bl;
        }
        // per-accumulator op order unchanged vs legacy: AhBh, AlBh, AhBl
        acc[0][nt] = __builtin_amdgcn_mfma_f32_16x16x32_bf16(Ah[0], Bh, acc[0][nt], 0, 0, 0);
        acc[0][nt] = __builtin_amdgcn_mfma_f32_16x16x32_bf16(Al[0], Bh, acc[0][nt], 0, 0, 0);
        acc[0][nt] = __builtin_amdgcn_mfma_f32_16x16x32_bf16(Ah[0], Bl, acc[0][nt], 0, 0, 0);
        acc[1][nt] = __builtin_amdgcn_mfma_f32_16x16x32_bf16(Ah[1], Bh, acc[1][nt], 0, 0, 0);
        acc[1][nt] = __builtin_amdgcn_mfma_f32_16x16x32_bf16(Al[1], Bh, acc[1][nt], 0, 0, 0);
        acc[1][nt] = __builtin_amdgcn_mfma_f32_16x16x32_bf16(Ah[1], Bl, acc[1][nt], 0, 0, 0);
      }
    }

    // epilogue: add bias, square, reduce this wave's 64 columns (l15 butterfly,
    // byte-identical to legacy per-ng computation)
    float bn[4];
    #pragma unroll
    for (int nt = 0; nt < 4; nt++) bn[nt] = sm.beL[(ng * 4 + nt) * 16 + l15];
    #pragma unroll
    for (int m2 = 0; m2 < 2; m2++){
      int mt = mh * 2 + m2;
      float er[4];
      #pragma unroll
      for (int r = 0; r < 4; r++){
        float s_ = 0.f;
        #pragma unroll
        for (int nt = 0; nt < 4; nt++){
          float hvv = acc[m2][nt][r] + bn[nt];
          s_ = fmaf(hvv, hvv, s_);
        }
        er[r] = s_;
      }
      #pragma unroll
      for (int x2 = 1; x2 < 16; x2 <<= 1){
        #pragma unroll
        for (int r = 0; r < 4; r++) er[r] += __shfl_xor(er[r], x2, 64);
      }
      if (l15 == 0){
        #pragma unroll
        for (int r = 0; r < 4; r++)
          sm.energyP[w][mt * 16 + quad * 4 + r] = er[r];
      }
    }
  }
  __syncthreads();
  // combine ng partials in legacy left-assoc ng order: (((ng0+ng1)+ng2)+ng3)
  if (tid < 96){
    float e = sm.energyP[0][tid];
    e += sm.energyP[1][tid];
    e += sm.energyP[2][tid];
    e += sm.energyP[3][tid];
    sm.energy[tid] = e;
  }
  __syncthreads();

  // argmax over 81 energies (padded rows >80 contain garbage — exclude them)
  float bvE = (tid < 81) ? sm.energy[tid] : -INFINITY;
  int   biE = (tid < 81) ? tid : 0;
  int ind = blockArgMax(sm, bvE, biE);

  // recompute selected row h[ind, j] EXACTLY in fp32; thread owns j = tid
  // (same per-j fmaf chain order as legacy -> bit-exact)
  int roff = 80 - ind;
  float hv = sm.beL[tid];
  #pragma unroll 8
  for (int w2 = 0; w2 < 80; w2++){
    float xv = sm.xp[80 + w2];
    hv = fmaf(xv, We[(w2 + roff) * 256 + tid], hv);
  }

  // hsr (thread's single j) — u64-key rank, bit-exact selection
  float vsq = hv * hv;
  unsigned long long myk = rankKey(vsq, tid);
  sm.hkey[tid] = myk;
  __syncthreads();
  int sel1 = rankTop64(sm, myk);
  unsigned char mpv = mask[tid];
  if (first){
    mask[tid] = (unsigned char)sel1;
    compactSel(sm, sel1, hv);
  } else {
    int st = sm.smask_t;
    float interv = (float)mpv * (float)sel1;
    if (interv > 0.f && !st){
      float dd = hv - (1.f - interv);
      lossAcc += dd * dd;
    }
    float h2 = (mpv > 0) ? 0.f : hv;
    __syncthreads();               // rank1 readers done before hkey rewrite
    unsigned long long myk2 = rankKey(h2 * h2, tid);
    sm.hkey[tid] = myk2;
    __syncthreads();
    int sel2 = rankTop64(sm, myk2);
    mask[tid] = (unsigned char)(mpv + (unsigned char)sel2);
    compactSel(sm, sel2, h2);
  }
  // compactSel ends with a barrier -> dpair ready

  // sparse decode over the exactly-64 selected rows (ascending idx => bit-exact):
  // ext[d] = bdec[d] + sum_{sel h asc} val_h * Wdec[h*160+d]; thread owns d = tid.
  // dpair.x is the pre-scaled byte offset h*640; base pointer hoisted.
  if (tid < 160){
    const char* wbase = (const char*)Wdec + (size_t)(tid * 4);
    float a = bdec[tid];
    #pragma unroll 8
    for (int i = 0; i < 64; i++){
      int2 p = sm.dpair[i];        // block-uniform broadcast, one b64 read
      a = fmaf(__int_as_float(p.y), *(const float*)(wbase + p.x), a);
    }
    sm.ext[tid] = a;
  }
  __syncthreads();

  float mv = fabsf((float)(theta - 79));
  bool gate = (mv > 40.0f);        // ETH
  if (tid < 80){
    float dec = sm.ext[ind + tid];
    dec_out[tid] = dec;            // residual update uses decoded output regardless of gates
    float diff = dec - target[tid];
    float l = (gate || sm.smask[tid]) ? 0.f : diff * diff;
    lossAcc += l / (mv + 1.0f);
  }
  __syncthreads();
}

__global__ void __launch_bounds__(64) zero_out_kernel(float* out){
  if (threadIdx.x == 0) out[0] = 0.f;
}

// Pre-repack We into MFMA B-fragment layout (bf16 hi and lo, interleaved):
// wsB[(tile*64+lane)*2 + {0,1}] = {hi, lo} fragment (16B each).
__global__ void __launch_bounds__(64) prep_we_kernel(
    const float* __restrict__ We, short8* __restrict__ wsB){
  int tile = blockIdx.x;
  int lane = threadIdx.x;
  int kt = tile >> 4, nt = tile & 15;
  int k0 = kt * 32 + (lane >> 4) * 8;
  int n  = nt * 16 + (lane & 15);
  short8 h, l;
  #pragma unroll
  for (int j = 0; j < 8; j++){
    float v = We[(k0 + j) * 256 + n];
    unsigned bits = __float_as_uint(v);
    unsigned hi = bits >> 16;
    float hif = __uint_as_float(hi << 16);
    unsigned lo = __float_as_uint(v - hif) >> 16;
    h[j] = (short)hi; l[j] = (short)lo;
  }
  int ti2 = (tile * 64 + lane) * 2;
  wsB[ti2]     = h;
  wsB[ti2 + 1] = l;
}

template<int USE_WS>
__global__ void __launch_bounds__(256, 4) net_kernel(
    const float* __restrict__ x,  const float* __restrict__ y,
    const float* __restrict__ We, const float* __restrict__ be,
    const float* __restrict__ Wd, const float* __restrict__ bd,
    const float* __restrict__ Wds,const float* __restrict__ bds,
    const short8* __restrict__ wsB,
    float* out)
{
  __shared__ SM sm;
  int tid = threadIdx.x;
  int lane = tid & 63, w = tid >> 6;
  int bt  = blockIdx.x;
  const float* xin = x + bt * 80;
  const float* yin = y + bt * 80;

  if (tid < 80){
    sm.xres[tid] = xin[tid];
    float yv = yin[tid];
    sm.yres[tid] = yv;
    sm.smask[tid] = (yv == 0.f) ? 1 : 0;   // seq_mask from ORIGINAL y
  }
  sm.mp_self[tid] = 0;
  sm.mp_src[tid]  = 0;
  sm.beL[tid] = be[tid];
  __syncthreads();
  if (w == 0){
    int c = 0;
    for (int i = lane; i < 80; i += 64) c += (int)sm.smask[i];
    int total = waveSumI(c);
    if (lane == 0) sm.smask_t = (total == 80) ? 1 : 0;
  }
  __syncthreads();

  float lossAcc = 0.f;

  for (int it = 0; it < 4; it++){
    bool first = (it == 0);

    // --- align x_res to y_res (computes nys for this iteration) ---
    int th1 = simArgmax(sm, sm.xres, sm.yal, 1);

    // --- attention softmax(y_al * y_res) and z = y_al * attn ---
    // order-sensitive sum: wave 0 runs the byte-identical legacy code
    if (w == 0){
      float p0 = sm.yal[lane] * sm.yres[lane];
      float p1 = (lane < 16) ? sm.yal[64 + lane] * sm.yres[64 + lane] : -INFINITY;
      float mx = waveMax(fmaxf(p0, p1));
      float e0 = expf(p0 - mx);
      float e1 = (lane < 16) ? expf(p1 - mx) : 0.f;
      float ssum = waveSum(e0 + e1);
      sm.zb[lane] = sm.yal[lane] * (e0 / ssum);
      if (lane < 16) sm.zb[64 + lane] = sm.yal[64 + lane] * (e1 / ssum);
    }
    __syncthreads();

    // --- reverse shift: x_ele[d] = z[d + 79 - theta] ---
    if (tid < 80){
      int q = tid + 79 - th1;
      sm.xele[tid] = (q >= 0 && q < 80) ? sm.zb[q] : 0.f;
    }

    // --- self branch ---
    branchCompute<USE_WS>(sm, We, wsB, Wds, bds,
                          sm.xele, sm.mp_self, sm.xres, sm.xele, th1, first, lossAcc);

    // --- re-align decoded x_ele to y_res (yres unchanged -> reuse nys) ---
    int th2 = simArgmax(sm, sm.xele, sm.yal, 0);

    // --- src branch ---
    branchCompute<USE_WS>(sm, We, wsB, Wd, bd,
                          sm.yal, sm.mp_src, sm.yres, sm.decsrc, th2, first, lossAcc);

    // --- residual updates ---
    __syncthreads();
    if (tid < 80){
      sm.xres[tid] -= sm.xele[tid];
      sm.yres[tid] -= sm.decsrc[tid];
    }
    __syncthreads();
  }

  // block loss reduction: per-wave butterfly, then fixed-order 4-way sum
  float vsum = waveSum(lossAcc);
  if (lane == 0) sm.abv[w] = vsum;
  __syncthreads();
  if (tid == 0){
    float total = ((sm.abv[0] + sm.abv[1]) + sm.abv[2]) + sm.abv[3];
    atomicAdd(out, total * 0.25f);   // mean over 4 iterations
  }
}

extern "C" void kernel_launch(void* const* d_in, const int* in_sizes, int n_in,
                              void* d_out, int out_size, void* d_ws, size_t ws_size,
                              hipStream_t stream) {
  const float* x   = (const float*)d_in[0];
  const float* y   = (const float*)d_in[1];
  const float* We  = (const float*)d_in[2];
  const float* be  = (const float*)d_in[3];
  const float* Wd  = (const float*)d_in[4];
  const float* bd  = (const float*)d_in[5];
  const float* Wds = (const float*)d_in[6];
  const float* bds = (const float*)d_in[7];
  float* out = (float*)d_out;

  // We-fragment repack buffer: 80 tiles x 64 lanes x {hi,lo} x 16B = 160 KiB
  const size_t fragCount = 80 * 64 * 2;                 // short8 elements
  const size_t fragBytes = fragCount * sizeof(short8);  // 163840 B
  int use_ws = (ws_size >= fragBytes) ? 1 : 0;
  short8* wsB = (short8*)d_ws;

  hipLaunchKernelGGL(zero_out_kernel, dim3(1), dim3(64), 0, stream, out);
  if (use_ws){
    hipLaunchKernelGGL(prep_we_kernel, dim3(80), dim3(64), 0, stream, We, wsB);
    hipLaunchKernelGGL((net_kernel<1>), dim3(NBT), dim3(256), 0, stream,
                       x, y, We, be, Wd, bd, Wds, bds, wsB, out);
  } else {
    hipLaunchKernelGGL((net_kernel<0>), dim3(NBT), dim3(256), 0, stream,
                       x, y, We, be, Wd, bd, Wds, bds, wsB, out);
  }
}

// Round 12
// 630.218 us; speedup vs baseline: 1.0769x; 1.0045x over previous
//
#include <hip/hip_runtime.h>
#include <math.h>

// Problem constants (B=8, T=256 -> 2048 independent (b,t) pipelines)
// R17: safe issue-slot/barrier bundle on the R16 champion (633 us).
// History: complex restructures 0/4, targeted exact cuts 5/5 -> cuts only:
//  1) hkey2 second key array: non-first branches write both rank key sets
//     before ONE barrier (h2 depends only on mpv, known early) -> removes
//     the hkey-rewrite guard barrier pair (x6 branches).
//  2) rank loop uses 4 independent accumulators (breaks 256-long addc chain).
//  3) xp[] deleted: row recompute reads enc_in[] directly (same values).
//  4) beL[] deleted: bias (be[tid], bn[4]) hoisted to registers ONCE from
//     global (iteration-invariant).
//  5) compactSel 'below' mask precomputed per thread.
#define NBT 2048

typedef __attribute__((ext_vector_type(8))) short short8;     // 8 bf16 (4 VGPRs)
typedef __attribute__((ext_vector_type(4))) float floatx4;    // MFMA C/D

struct SM {
  alignas(16) short xhr[8][264];    // rotated bf16-hi copies: xhr[c][i] = hi(xp[c+i])
  alignas(16) short xlr[8][264];    // rotated bf16-lo copies
  alignas(16) unsigned long long hkey[256];  // rank keys pass 1
  alignas(16) unsigned long long hkey2[256]; // rank keys pass 2 (non-first)
  alignas(16) float yres[80];
  alignas(16) float spadr[4][244];  // rotated sim windows: spadr[c][i] = spad[i+c]
  alignas(16) int2  dpair[64];      // compacted (byte-offset idx*640, float-bits)
  alignas(16) float energyP[4][96]; // per-wave (per-ng) energy partials
  float xres[80];
  float yal[80];
  float xele[80];
  float decsrc[80];
  float zb[80];
  float energy[96];                 // 81 valid + pad (6 m-tiles of 16)
  unsigned char mp_self[256];
  unsigned char mp_src[256];
  float ext[160];
  unsigned char smask[80];
  int smask_t;
  // cross-wave scratch
  float abv[4];
  int   abi[4];
  int   wcnt[4];
  float nys;
};

// ---- wave-level primitives (64 lanes, butterfly -> all lanes hold result) ----
__device__ __forceinline__ float waveSum(float v){
  #pragma unroll
  for (int off = 32; off > 0; off >>= 1) v += __shfl_xor(v, off, 64);
  return v;
}
__device__ __forceinline__ int waveSumI(int v){
  #pragma unroll
  for (int off = 32; off > 0; off >>= 1) v += __shfl_xor(v, off, 64);
  return v;
}
__device__ __forceinline__ float waveMax(float v){
  #pragma unroll
  for (int off = 32; off > 0; off >>= 1) v = fmaxf(v, __shfl_xor(v, off, 64));
  return v;
}

// block-wide argmax, JAX tie rule (lowest index wins). Max + min-index is
// associative, so any reduction structure yields the unique answer.
__device__ __forceinline__ int blockArgMax(SM& sm, float v, int idx){
  int lane = threadIdx.x & 63, w = threadIdx.x >> 6;
  #pragma unroll
  for (int off = 32; off > 0; off >>= 1){
    float ov = __shfl_xor(v,   off, 64);
    int   oi = __shfl_xor(idx, off, 64);
    if (ov > v || (ov == v && oi < idx)){ v = ov; idx = oi; }
  }
  if (lane == 0){ sm.abv[w] = v; sm.abi[w] = idx; }
  __syncthreads();
  float bv = sm.abv[0]; int bi = sm.abi[0];
  #pragma unroll
  for (int w2 = 1; w2 < 4; w2++){
    float ov = sm.abv[w2]; int oi = sm.abi[w2];
    if (ov > bv || (ov == bv && oi < bi)){ bv = ov; bi = oi; }
  }
  __syncthreads();   // abv/abi free for reuse after this
  return bi;
}

// top-64 membership via rank over u64 integer keys. vsq >= 0 (squares) =>
// IEEE bits monotone => key_i > key_j <=> v_i > v_j || (v_i==v_j && i<j).
// rank = #{key_i > key_j}; selected iff rank < 64. Keys unique by index =>
// exactly 64 selected. Reads are block-uniform -> LDS broadcast. Fixed
// 128-iteration loop; 4 independent accumulators break the addc chain.
__device__ __forceinline__ int rankTop64(const unsigned long long* keys,
                                         unsigned long long mykey){
  int c0 = 0, c1 = 0, c2 = 0, c3 = 0;
  const ulonglong2* q2 = (const ulonglong2*)keys;
  #pragma unroll 4
  for (int i2 = 0; i2 < 128; i2 += 2){
    ulonglong2 oa = q2[i2];
    ulonglong2 ob = q2[i2 + 1];
    c0 += (oa.x > mykey) ? 1 : 0;
    c1 += (oa.y > mykey) ? 1 : 0;
    c2 += (ob.x > mykey) ? 1 : 0;
    c3 += (ob.y > mykey) ? 1 : 0;
  }
  int cnt = (c0 + c1) + (c2 + c3);
  return (cnt < 64) ? 1 : 0;
}
__device__ __forceinline__ unsigned long long rankKey(float vsq, int j){
  return (((unsigned long long)__float_as_uint(vsq)) << 8)
       | (unsigned long long)(255 - j);
}

// Compact the exactly-64 selected (offset,value) pairs into an ascending-index
// LDS list: per-wave ballot + cross-wave popcount prefix. Ascending order =>
// decode accumulation order matches the reference bit-exactly. The stored
// .x is the PRE-SCALED byte offset idx*640 (Wdec rows are 160 floats).
__device__ __forceinline__ void compactSel(SM& sm, int sel, float val,
                                           unsigned long long below){
  int tid = threadIdx.x, lane = tid & 63, w = tid >> 6;
  unsigned long long mq = __ballot(sel != 0);
  if (lane == 0) sm.wcnt[w] = __popcll(mq);
  __syncthreads();
  int base = 0;
  #pragma unroll
  for (int i = 0; i < 4; i++) base += (i < w) ? sm.wcnt[i] : 0;
  if (sel){
    int pos = base + (int)__popcll(mq & below);
    sm.dpair[pos] = make_int2(tid * 640, __float_as_int(val));
  }
  __syncthreads();   // list ready
}

// sim_argmax: cosine sim over 159 shifts of src vs yres; thread t owns shift t.
// Per-shift fmaf chain order identical to legacy (bit-exact sims). spad is
// held as 4 rotated copies so each thread's 4-wide window read is one
// aligned ds_read_b128 (values bit-identical). nys computed by wave 0
// (legacy butterfly) only when doNy != 0 — yres invariant within iteration.
__device__ __forceinline__ int simArgmax(SM& sm, const float* src, float* yal_out, int doNy){
  int tid = threadIdx.x;
  int lane = tid & 63, w = tid >> 6;
  __syncthreads();
  {
    float v = (tid >= 79 && tid < 159) ? src[tid - 79] : 0.f;
    #pragma unroll
    for (int c = 0; c < 4; c++){
      int i = tid - c;
      if (i >= 0 && i < 240){ sm.spadr[c][i] = v; }
    }
  }
  if (doNy && w == 0){
    float yv2 = 0.f;
    for (int i = lane; i < 80; i += 64){ float yv = sm.yres[i]; yv2 = fmaf(yv, yv, yv2); }
    float ny = sqrtf(waveSum(yv2));
    if (lane == 0) sm.nys = ny;
  }
  __syncthreads();
  float nys = sm.nys;
  float bv = -INFINITY; int bi = 0;
  if (tid < 159){
    const int c = tid & 3;
    const float4* xr = (const float4*)&sm.spadr[c][tid - c];  // 16B aligned
    const float4* y4p = (const float4*)sm.yres;
    float num = 0.f, nx = 0.f;
    for (int w4 = 0; w4 < 20; w4++){
      float4 yy = y4p[w4];
      float4 xa = xr[w4];          // = spad[tid+4w4 .. +3], bit-identical
      num = fmaf(xa.x, yy.x, num); nx = fmaf(xa.x, xa.x, nx);
      num = fmaf(xa.y, yy.y, num); nx = fmaf(xa.y, xa.y, nx);
      num = fmaf(xa.z, yy.z, num); nx = fmaf(xa.z, xa.z, nx);
      num = fmaf(xa.w, yy.w, num); nx = fmaf(xa.w, xa.w, nx);
    }
    bv = num / (sqrtf(nx) * nys + 1e-6f);
    bi = tid;
  }
  int th = blockArgMax(sm, bv, bi);
  if (tid < 80) yal_out[tid] = sm.spadr[0][th + tid];
  __syncthreads();
  return th;
}

// One branch: MFMA energy (split bf16, kt-trimmed — bit-safe; wave w owns
// n-group w, partials summed in legacy ng order; A-frags read as single
// aligned b128 from rotated copies; B-frags streamed per n-tile), argmax,
// exact fp32 row recompute (1 j/thread, reads enc_in directly), hsr
// (u64-key dual-array rank), sparse decode (1 d/thread), masked loss.
template<int USE_WS>
__device__ __forceinline__ void branchCompute(
    SM& sm, const float* __restrict__ We,
    const short8* __restrict__ wsB,
    const float* __restrict__ Wdec, const float* __restrict__ bdec,
    const float* enc_in, unsigned char* mask, const float* target,
    float* dec_out, int theta, bool first, float& lossAcc,
    float bias_j, const float bn[4], unsigned long long below)
{
  int tid = threadIdx.x;
  int lane = tid & 63, w = tid >> 6;
  int quad = lane >> 4, l15 = lane & 15;
  __syncthreads();
  {
    float v = (tid >= 80 && tid < 160) ? enc_in[tid - 80] : 0.f;
    unsigned bits = __float_as_uint(v);
    unsigned hi = bits >> 16;
    float hif = __uint_as_float(hi << 16);
    unsigned lo = __float_as_uint(v - hif) >> 16;
    short hs = (short)hi, ls = (short)lo;
    // rotated copies: xhr[c][i] = hi(xp[c+i]); A-frag base ≡ l15 (mod 8)
    // -> each fragment is one aligned 16B read. Values bit-identical.
    #pragma unroll
    for (int c = 0; c < 8; c++){
      int i = tid - c;
      if (i >= 0){ sm.xhr[c][i] = hs; sm.xlr[c][i] = ls; }
    }
  }
  __syncthreads();

  const floatx4 zero4 = {0.f, 0.f, 0.f, 0.f};
  const int ng = w;                  // wave w owns n-group w (4 n-tiles)
  const int c8 = l15 & 7;
  const int hb = l15 >> 3;

  #pragma unroll 1
  for (int mh = 0; mh < 3; mh++){    // 2 m-tiles per pass (acc = 32 regs)
    int ktlo = (mh == 0) ? 1 : 0;    // nonzero-support kt range for these m rows
    int kthi = 5 - mh;               // (skipped products are exactly 0 -> bit-safe)
    floatx4 acc[2][4];
    #pragma unroll
    for (int m2 = 0; m2 < 2; m2++)
      #pragma unroll
      for (int nt = 0; nt < 4; nt++) acc[m2][nt] = zero4;

    #pragma unroll 1
    for (int kt = ktlo; kt < kthi; kt++){
      // A fragments for this kt, both m-tiles: single aligned b128 each.
      // base = mt*16 + l15 + kt*32 + quad*8 = (l15&7) + 8*kb
      short8 Ah[2], Al[2];
      #pragma unroll
      for (int m2 = 0; m2 < 2; m2++){
        int mt = mh * 2 + m2;
        int kb = quad + 2 * mt + 4 * kt + hb;
        Ah[m2] = *reinterpret_cast<const short8*>(&sm.xhr[c8][8 * kb]);
        Al[m2] = *reinterpret_cast<const short8*>(&sm.xlr[c8][8 * kb]);
      }
      // stream B per n-tile: only one (Bh,Bl) pair live at a time (x2 unroll)
      #pragma unroll 2
      for (int nt = 0; nt < 4; nt++){
        short8 Bh, Bl;
        int tileIdx = kt * 16 + (ng * 4 + nt);
        if (USE_WS){
          int ti2 = (tileIdx * 64 + lane) * 2;
          Bh = wsB[ti2];
          Bl = wsB[ti2 + 1];
        } else {
          short8 bh, bl;
          int k0 = kt * 32 + quad * 8;
          int n  = (ng * 4 + nt) * 16 + l15;
          #pragma unroll
          for (int j = 0; j < 8; j++){
            float v = We[(k0 + j) * 256 + n];
            unsigned bits = __float_as_uint(v);
            unsigned hi = bits >> 16;
            float hif = __uint_as_float(hi << 16);
            unsigned lo = __float_as_uint(v - hif) >> 16;
            bh[j] = (short)hi; bl[j] = (short)lo;
          }
          Bh = bh; Bl = bl;
        }
        // per-accumulator op order unchanged vs legacy: AhBh, AlBh, AhBl
        acc[0][nt] = __builtin_amdgcn_mfma_f32_16x16x32_bf16(Ah[0], Bh, acc[0][nt], 0, 0, 0);
        acc[0][nt] = __builtin_amdgcn_mfma_f32_16x16x32_bf16(Al[0], Bh, acc[0][nt], 0, 0, 0);
        acc[0][nt] = __builtin_amdgcn_mfma_f32_16x16x32_bf16(Ah[0], Bl, acc[0][nt], 0, 0, 0);
        acc[1][nt] = __builtin_amdgcn_mfma_f32_16x16x32_bf16(Ah[1], Bh, acc[1][nt], 0, 0, 0);
        acc[1][nt] = __builtin_amdgcn_mfma_f32_16x16x32_bf16(Al[1], Bh, acc[1][nt], 0, 0, 0);
        acc[1][nt] = __builtin_amdgcn_mfma_f32_16x16x32_bf16(Ah[1], Bl, acc[1][nt], 0, 0, 0);
      }
    }

    // epilogue: add bias, square, reduce this wave's 64 columns (l15 butterfly,
    // byte-identical to legacy per-ng computation); bn hoisted to registers
    #pragma unroll
    for (int m2 = 0; m2 < 2; m2++){
      int mt = mh * 2 + m2;
      float er[4];
      #pragma unroll
      for (int r = 0; r < 4; r++){
        float s_ = 0.f;
        #pragma unroll
        for (int nt = 0; nt < 4; nt++){
          float hvv = acc[m2][nt][r] + bn[nt];
          s_ = fmaf(hvv, hvv, s_);
        }
        er[r] = s_;
      }
      #pragma unroll
      for (int x2 = 1; x2 < 16; x2 <<= 1){
        #pragma unroll
        for (int r = 0; r < 4; r++) er[r] += __shfl_xor(er[r], x2, 64);
      }
      if (l15 == 0){
        #pragma unroll
        for (int r = 0; r < 4; r++)
          sm.energyP[w][mt * 16 + quad * 4 + r] = er[r];
      }
    }
  }
  __syncthreads();
  // combine ng partials in legacy left-assoc ng order: (((ng0+ng1)+ng2)+ng3)
  if (tid < 96){
    float e = sm.energyP[0][tid];
    e += sm.energyP[1][tid];
    e += sm.energyP[2][tid];
    e += sm.energyP[3][tid];
    sm.energy[tid] = e;
  }
  __syncthreads();

  // argmax over 81 energies (padded rows >80 contain garbage — exclude them)
  float bvE = (tid < 81) ? sm.energy[tid] : -INFINITY;
  int   biE = (tid < 81) ? tid : 0;
  int ind = blockArgMax(sm, bvE, biE);

  // recompute selected row h[ind, j] EXACTLY in fp32; thread owns j = tid.
  // enc_in[w2] == legacy xp[80+w2] (pads never read) -> bit-exact chain.
  int roff = 80 - ind;
  float hv = bias_j;
  #pragma unroll 8
  for (int w2 = 0; w2 < 80; w2++){
    float xv = enc_in[w2];
    hv = fmaf(xv, We[(w2 + roff) * 256 + tid], hv);
  }

  // hsr (thread's single j) — u64-key rank, bit-exact selection
  float vsq = hv * hv;
  unsigned long long myk = rankKey(vsq, tid);
  unsigned char mpv = mask[tid];
  if (first){
    sm.hkey[tid] = myk;
    __syncthreads();
    int sel1 = rankTop64(sm.hkey, myk);
    mask[tid] = (unsigned char)sel1;
    compactSel(sm, sel1, hv, below);
  } else {
    // h2 depends only on mpv (known now) -> write BOTH key arrays, 1 barrier
    float h2 = (mpv > 0) ? 0.f : hv;
    unsigned long long myk2 = rankKey(h2 * h2, tid);
    sm.hkey[tid]  = myk;
    sm.hkey2[tid] = myk2;
    __syncthreads();
    int sel1 = rankTop64(sm.hkey,  myk);
    int sel2 = rankTop64(sm.hkey2, myk2);
    int st = sm.smask_t;
    float interv = (float)mpv * (float)sel1;
    if (interv > 0.f && !st){
      float dd = hv - (1.f - interv);
      lossAcc += dd * dd;
    }
    mask[tid] = (unsigned char)(mpv + (unsigned char)sel2);
    compactSel(sm, sel2, h2, below);
  }
  // compactSel ends with a barrier -> dpair ready

  // sparse decode over the exactly-64 selected rows (ascending idx => bit-exact):
  // ext[d] = bdec[d] + sum_{sel h asc} val_h * Wdec[h*160+d]; thread owns d = tid.
  // dpair.x is the pre-scaled byte offset h*640; base pointer hoisted.
  if (tid < 160){
    const char* wbase = (const char*)Wdec + (size_t)(tid * 4);
    float a = bdec[tid];
    #pragma unroll 8
    for (int i = 0; i < 64; i++){
      int2 p = sm.dpair[i];        // block-uniform broadcast, one b64 read
      a = fmaf(__int_as_float(p.y), *(const float*)(wbase + p.x), a);
    }
    sm.ext[tid] = a;
  }
  __syncthreads();

  float mv = fabsf((float)(theta - 79));
  bool gate = (mv > 40.0f);        // ETH
  if (tid < 80){
    float dec = sm.ext[ind + tid];
    dec_out[tid] = dec;            // residual update uses decoded output regardless of gates
    float diff = dec - target[tid];
    float l = (gate || sm.smask[tid]) ? 0.f : diff * diff;
    lossAcc += l / (mv + 1.0f);
  }
  __syncthreads();
}

__global__ void __launch_bounds__(64) zero_out_kernel(float* out){
  if (threadIdx.x == 0) out[0] = 0.f;
}

// Pre-repack We into MFMA B-fragment layout (bf16 hi and lo, interleaved):
// wsB[(tile*64+lane)*2 + {0,1}] = {hi, lo} fragment (16B each).
__global__ void __launch_bounds__(64) prep_we_kernel(
    const float* __restrict__ We, short8* __restrict__ wsB){
  int tile = blockIdx.x;
  int lane = threadIdx.x;
  int kt = tile >> 4, nt = tile & 15;
  int k0 = kt * 32 + (lane >> 4) * 8;
  int n  = nt * 16 + (lane & 15);
  short8 h, l;
  #pragma unroll
  for (int j = 0; j < 8; j++){
    float v = We[(k0 + j) * 256 + n];
    unsigned bits = __float_as_uint(v);
    unsigned hi = bits >> 16;
    float hif = __uint_as_float(hi << 16);
    unsigned lo = __float_as_uint(v - hif) >> 16;
    h[j] = (short)hi; l[j] = (short)lo;
  }
  int ti2 = (tile * 64 + lane) * 2;
  wsB[ti2]     = h;
  wsB[ti2 + 1] = l;
}

template<int USE_WS>
__global__ void __launch_bounds__(256, 4) net_kernel(
    const float* __restrict__ x,  const float* __restrict__ y,
    const float* __restrict__ We, const float* __restrict__ be,
    const float* __restrict__ Wd, const float* __restrict__ bd,
    const float* __restrict__ Wds,const float* __restrict__ bds,
    const short8* __restrict__ wsB,
    float* out)
{
  __shared__ SM sm;
  int tid = threadIdx.x;
  int lane = tid & 63, w = tid >> 6;
  int bt  = blockIdx.x;
  const float* xin = x + bt * 80;
  const float* yin = y + bt * 80;

  if (tid < 80){
    sm.xres[tid] = xin[tid];
    float yv = yin[tid];
    sm.yres[tid] = yv;
    sm.smask[tid] = (yv == 0.f) ? 1 : 0;   // seq_mask from ORIGINAL y
  }
  sm.mp_self[tid] = 0;
  sm.mp_src[tid]  = 0;
  // bias hoists: iteration/branch-invariant, from global, once
  const int l15i = lane & 15;
  float bias_j = be[tid];
  float bn[4];
  #pragma unroll
  for (int nt = 0; nt < 4; nt++) bn[nt] = be[(w * 4 + nt) * 16 + l15i];
  const unsigned long long below =
      (lane == 0) ? 0ull : ((~0ull) >> (64 - lane));
  __syncthreads();
  if (w == 0){
    int c = 0;
    for (int i = lane; i < 80; i += 64) c += (int)sm.smask[i];
    int total = waveSumI(c);
    if (lane == 0) sm.smask_t = (total == 80) ? 1 : 0;
  }
  __syncthreads();

  float lossAcc = 0.f;

  for (int it = 0; it < 4; it++){
    bool first = (it == 0);

    // --- align x_res to y_res (computes nys for this iteration) ---
    int th1 = simArgmax(sm, sm.xres, sm.yal, 1);

    // --- attention softmax(y_al * y_res) and z = y_al * attn ---
    // order-sensitive sum: wave 0 runs the byte-identical legacy code
    if (w == 0){
      float p0 = sm.yal[lane] * sm.yres[lane];
      float p1 = (lane < 16) ? sm.yal[64 + lane] * sm.yres[64 + lane] : -INFINITY;
      float mx = waveMax(fmaxf(p0, p1));
      float e0 = expf(p0 - mx);
      float e1 = (lane < 16) ? expf(p1 - mx) : 0.f;
      float ssum = waveSum(e0 + e1);
      sm.zb[lane] = sm.yal[lane] * (e0 / ssum);
      if (lane < 16) sm.zb[64 + lane] = sm.yal[64 + lane] * (e1 / ssum);
    }
    __syncthreads();

    // --- reverse shift: x_ele[d] = z[d + 79 - theta] ---
    if (tid < 80){
      int q = tid + 79 - th1;
      sm.xele[tid] = (q >= 0 && q < 80) ? sm.zb[q] : 0.f;
    }

    // --- self branch ---
    branchCompute<USE_WS>(sm, We, wsB, Wds, bds,
                          sm.xele, sm.mp_self, sm.xres, sm.xele, th1, first,
                          lossAcc, bias_j, bn, below);

    // --- re-align decoded x_ele to y_res (yres unchanged -> reuse nys) ---
    int th2 = simArgmax(sm, sm.xele, sm.yal, 0);

    // --- src branch ---
    branchCompute<USE_WS>(sm, We, wsB, Wd, bd,
                          sm.yal, sm.mp_src, sm.yres, sm.decsrc, th2, first,
                          lossAcc, bias_j, bn, below);

    // --- residual updates ---
    __syncthreads();
    if (tid < 80){
      sm.xres[tid] -= sm.xele[tid];
      sm.yres[tid] -= sm.decsrc[tid];
    }
    __syncthreads();
  }

  // block loss reduction: per-wave butterfly, then fixed-order 4-way sum
  float vsum = waveSum(lossAcc);
  if (lane == 0) sm.abv[w] = vsum;
  __syncthreads();
  if (tid == 0){
    float total = ((sm.abv[0] + sm.abv[1]) + sm.abv[2]) + sm.abv[3];
    atomicAdd(out, total * 0.25f);   // mean over 4 iterations
  }
}

extern "C" void kernel_launch(void* const* d_in, const int* in_sizes, int n_in,
                              void* d_out, int out_size, void* d_ws, size_t ws_size,
                              hipStream_t stream) {
  const float* x   = (const float*)d_in[0];
  const float* y   = (const float*)d_in[1];
  const float* We  = (const float*)d_in[2];
  const float* be  = (const float*)d_in[3];
  const float* Wd  = (const float*)d_in[4];
  const float* bd  = (const float*)d_in[5];
  const float* Wds = (const float*)d_in[6];
  const float* bds = (const float*)d_in[7];
  float* out = (float*)d_out;

  // We-fragment repack buffer: 80 tiles x 64 lanes x {hi,lo} x 16B = 160 KiB
  const size_t fragCount = 80 * 64 * 2;                 // short8 elements
  const size_t fragBytes = fragCount * sizeof(short8);  // 163840 B
  int use_ws = (ws_size >= fragBytes) ? 1 : 0;
  short8* wsB = (short8*)d_ws;

  hipLaunchKernelGGL(zero_out_kernel, dim3(1), dim3(64), 0, stream, out);
  if (use_ws){
    hipLaunchKernelGGL(prep_we_kernel, dim3(80), dim3(64), 0, stream, We, wsB);
    hipLaunchKernelGGL((net_kernel<1>), dim3(NBT), dim3(256), 0, stream,
                       x, y, We, be, Wd, bd, Wds, bds, wsB, out);
  } else {
    hipLaunchKernelGGL((net_kernel<0>), dim3(NBT), dim3(256), 0, stream,
                       x, y, We, be, Wd, bd, Wds, bds, wsB, out);
  }
}